// Round 12
// baseline (514.953 us; speedup 1.0000x reference)
//
#include <hip/hip_runtime.h>
#include <stdint.h>

typedef unsigned char u8;
typedef unsigned short u16;
typedef unsigned int u32;
typedef __attribute__((ext_vector_type(8))) short short8;
typedef __attribute__((ext_vector_type(4))) float floatx4;

#define BN_EPS 1e-5f
#define NPB 64        // nodes per bucket (power of 2; bucket = dst >> NPB_SHIFT)
#define NPB_SHIFT 6
#define NBMAX 2048

__device__ __forceinline__ float bf2f(u16 u) { return __uint_as_float(((unsigned)u) << 16); }
__device__ __forceinline__ u16 f2bf(float f) {
  unsigned u = __float_as_uint(f);
  u += 0x7FFFu + ((u >> 16) & 1u);   // round-to-nearest-even
  return (u16)(u >> 16);
}

// ---------------------------------------------------------------------------
// zero the small control block (stats + bucket totals)
__global__ void k_init(float* __restrict__ stats, u32* __restrict__ bucketTotal) {
  for (int i = threadIdx.x; i < 1024; i += blockDim.x) stats[i] = 0.f;
  for (int i = threadIdx.x; i < NBMAX + 1; i += blockDim.x) bucketTotal[i] = 0u;
}

// ---------------------------------------------------------------------------
// fused: global sum-of-squares of directions + per-bucket dst histogram
__global__ void k_norm_hist(const int* __restrict__ ei, const float* __restrict__ pos,
                            int E, int NB, float* __restrict__ stats,
                            u32* __restrict__ bucketTotal) {
  __shared__ u32 lh[NBMAX];
  __shared__ float red[16];
  for (int i = threadIdx.x; i < NB; i += blockDim.x) lh[i] = 0u;
  __syncthreads();
  int tid = blockIdx.x * blockDim.x + threadIdx.x;
  int stride = gridDim.x * blockDim.x;
  float acc = 0.f;
  for (int e = tid; e < E; e += stride) {
    int s = ei[e], d = ei[E + e];
    float d0 = pos[3 * s + 0] - pos[3 * d + 0];
    float d1 = pos[3 * s + 1] - pos[3 * d + 1];
    float d2 = pos[3 * s + 2] - pos[3 * d + 2];
    acc = fmaf(d0, d0, acc);
    acc = fmaf(d1, d1, acc);
    acc = fmaf(d2, d2, acc);
    atomicAdd(&lh[d >> NPB_SHIFT], 1u);
  }
#pragma unroll
  for (int off = 32; off > 0; off >>= 1) acc += __shfl_down(acc, off, 64);
  if ((threadIdx.x & 63) == 0) red[threadIdx.x >> 6] = acc;
  __syncthreads();
  if (threadIdx.x == 0) {
    float s = 0.f;
    for (int w = 0; w < (int)(blockDim.x >> 6); w++) s += red[w];
    atomicAdd(&stats[0], s);
  }
  for (int i = threadIdx.x; i < NB; i += blockDim.x)
    if (lh[i]) atomicAdd(&bucketTotal[i], lh[i]);
}

// ---------------------------------------------------------------------------
// exclusive scan of bucket totals — single wave, shfl prefix scan
__global__ void k_scan(const u32* __restrict__ bucketTotal, u32* __restrict__ base,
                       u32* __restrict__ cursor, int NB) {
  int lane = threadIdx.x;  // launched with 64 threads, 1 block
  u32 run = 0;
  for (int b0 = 0; b0 < NB; b0 += 64) {
    int b = b0 + lane;
    u32 v = (b < NB) ? bucketTotal[b] : 0u;
    u32 s = v;
#pragma unroll
    for (int off = 1; off < 64; off <<= 1) {
      u32 t = __shfl_up(s, off, 64);
      if (lane >= off) s += t;
    }
    u32 excl = run + s - v;
    if (b < NB) { base[b] = excl; cursor[b] = excl; }
    run += __shfl(s, 63, 64);   // broadcast chunk total
  }
  if (lane == 0) base[NB] = run;
}

// ---------------------------------------------------------------------------
// bin edges by dst bucket: sorted2[slot] = {src, dst} (coalesced-consumable
// downstream) + ln8[slot] = dst & 63 (compact lane id for bucket_max).
__global__ void k_place(const int* __restrict__ ei, int E, int NB,
                        u32* __restrict__ cursor, uint2* __restrict__ sorted2,
                        u8* __restrict__ ln8) {
  __shared__ u32 lh[NBMAX];
  __shared__ u32 lbase[NBMAX];
  for (int i = threadIdx.x; i < NB; i += blockDim.x) lh[i] = 0u;
  __syncthreads();
  int tid = blockIdx.x * blockDim.x + threadIdx.x;
  int stride = gridDim.x * blockDim.x;
  for (int e = tid; e < E; e += stride) atomicAdd(&lh[ei[E + e] >> NPB_SHIFT], 1u);
  __syncthreads();
  for (int i = threadIdx.x; i < NB; i += blockDim.x) {
    u32 c = lh[i];
    lbase[i] = c ? atomicAdd(&cursor[i], c) : 0u;
    lh[i] = 0u;
  }
  __syncthreads();
  for (int e = tid; e < E; e += stride) {
    int s = ei[e];
    int d = ei[E + e];
    int b = d >> NPB_SHIFT;
    u32 slot = lbase[b] + atomicAdd(&lh[b], 1u);
    sorted2[slot] = make_uint2((u32)s, (u32)d);
    ln8[slot] = (u8)(d & (NPB - 1));
  }
}

// ---------------------------------------------------------------------------
// stats-only layer 1: identical math to k_layer1 phase A/B (incl. bf16
// rounding) but NO h store — produces gsum1/gsq1 for the BN1 fold.
__global__ __launch_bounds__(256) void k_stats1(
    const float* __restrict__ pos, const float* __restrict__ x,
    const float* __restrict__ W1, const float* __restrict__ b1,
    const float* __restrict__ stats, float* __restrict__ gsum,
    float* __restrict__ gsq, int E, const uint2* __restrict__ sorted2) {
  __shared__ float in6[6][256];
  __shared__ float ssum[64], ssq[64];
  float invn = 1.0f / sqrtf(stats[0]);
  int t = threadIdx.x;
  int lane = t & 63;
  int wv = t >> 6;
  int eslot = lane >> 3;
  int c0 = (lane & 7) * 8;
  float w[6][8];
#pragma unroll
  for (int k = 0; k < 6; k++)
#pragma unroll
    for (int j = 0; j < 8; j++) w[k][j] = W1[k * 64 + c0 + j];
  float bias[8];
#pragma unroll
  for (int j = 0; j < 8; j++) bias[j] = b1[c0 + j];
  float psum[8] = {0.f, 0.f, 0.f, 0.f, 0.f, 0.f, 0.f, 0.f};
  float psq[8] = {0.f, 0.f, 0.f, 0.f, 0.f, 0.f, 0.f, 0.f};

  int chunks = (E + 255) >> 8;
  for (int c = blockIdx.x; c < chunks; c += gridDim.x) {
    long e0 = (long)c << 8;
    int e = (int)e0 + t;
    float v[6] = {0.f, 0.f, 0.f, 0.f, 0.f, 0.f};
    if (e < E) {
      uint2 sd = sorted2[e];
      int s = (int)sd.x, d = (int)sd.y;
      float p0 = pos[3 * s + 0], p1 = pos[3 * s + 1], p2 = pos[3 * s + 2];
      float q0 = pos[3 * d + 0], q1 = pos[3 * d + 1], q2 = pos[3 * d + 2];
      v[0] = (p0 - q0) * invn;
      v[1] = (p1 - q1) * invn;
      v[2] = (p2 - q2) * invn;
      v[3] = x[3 * d + 0];
      v[4] = x[3 * d + 1];
      v[5] = x[3 * d + 2];
    }
    __syncthreads();
#pragma unroll
    for (int k = 0; k < 6; k++) in6[k][t] = v[k];
    __syncthreads();
    int lim = E - (int)e0;
    if (lim > 256) lim = 256;
#pragma unroll
    for (int i = 0; i < 8; i++) {
      int el = wv * 64 + i * 8 + eslot;
      if (el >= lim) continue;
      float inr[6];
#pragma unroll
      for (int k = 0; k < 6; k++) inr[k] = in6[k][el];
#pragma unroll
      for (int j = 0; j < 8; j++) {
        float acc = bias[j];
#pragma unroll
        for (int k = 0; k < 6; k++) acc = fmaf(inr[k], w[k][j], acc);
        float hf = bf2f(f2bf(fmaxf(acc, 0.f)));
        psum[j] += hf;
        psq[j] = fmaf(hf, hf, psq[j]);
      }
    }
  }
  if (t < 64) { ssum[t] = 0.f; ssq[t] = 0.f; }
  __syncthreads();
#pragma unroll
  for (int j = 0; j < 8; j++) {
    atomicAdd(&ssum[c0 + j], psum[j]);
    atomicAdd(&ssq[c0 + j], psq[j]);
  }
  __syncthreads();
  if (t < 64) {
    atomicAdd(&gsum[t], ssum[t]);
    atomicAdd(&gsq[t], ssq[t]);
  }
}

// ---------------------------------------------------------------------------
// FUSED layer1 + layer2: h1 lives only in a 32 KB swizzled LDS stage; HBM
// sees only the input gathers and the h2 write (h1's 410 MB round-trip
// deleted). Per 256-edge chunk: phase A gather -> in6; phase B computes h1
// (W1 from LDS) -> stage (uint4 writes, slot ^= el&7 swizzle); MFMA phase
// reads A-frags from stage (full-bank-BW b128 reads) and runs the proven
// non-swap mfma body: h2 global write + stats2.
__global__ __launch_bounds__(256) void k_layer12(
    const float* __restrict__ pos, const float* __restrict__ x,
    const float* __restrict__ W1, const float* __restrict__ b1,
    const float* __restrict__ stats, const uint2* __restrict__ sorted2,
    const float* __restrict__ W2, const float* __restrict__ b2,
    const float* __restrict__ gsum_in, const float* __restrict__ gsq_in,
    const float* __restrict__ g_in, const float* __restrict__ be_in,
    float invE, u16* __restrict__ h, float* __restrict__ gsum,
    float* __restrict__ gsq, int E) {
  __shared__ float sc_s[64], sh_s[64];
  __shared__ float w1s[384];
  __shared__ float b1s[64];
  __shared__ float in6[6][256];
  __shared__ __attribute__((aligned(16))) u16 stage[256 * 64];  // 32 KB
  __shared__ float ssum[64], ssq[64];

  if (threadIdx.x < 64) {  // BN1 finalize
    int c = threadIdx.x;
    float mu = gsum_in[c] * invE;
    float var = gsq_in[c] * invE - mu * mu;
    float s = g_in[c] * rsqrtf(var + BN_EPS);
    sc_s[c] = s;
    sh_s[c] = be_in[c] - mu * s;
    b1s[c] = b1[c];
  }
  for (int i = threadIdx.x; i < 384; i += blockDim.x) w1s[i] = W1[i];
  __syncthreads();

  int lane = threadIdx.x & 63;
  int m = lane & 15;
  int q = lane >> 4;
  int wv = threadIdx.x >> 6;
  int eslot = lane >> 3;
  int c0 = (lane & 7) * 8;

  // W2 frags + folded bias (identical to k_layer_mfma prologue)
  short8 bf[4][2];
  float bias2[4];
#pragma unroll
  for (int t = 0; t < 4; t++) {
    int n = t * 16 + m;
    float bb = b2[n];
    for (int k = 0; k < 64; k++) bb = fmaf(sh_s[k], W2[k * 64 + n], bb);
    bias2[t] = bb;
#pragma unroll
    for (int s = 0; s < 2; s++)
#pragma unroll
      for (int j = 0; j < 8; j++) {
        int k = s * 32 + q * 8 + j;
        bf[t][s][j] = (short)f2bf(W2[k * 64 + n] * sc_s[k]);
      }
  }

  float invn = 1.0f / sqrtf(stats[0]);
  float psum[4] = {0.f, 0.f, 0.f, 0.f}, psq[4] = {0.f, 0.f, 0.f, 0.f};

  int chunks = (E + 255) >> 8;
  for (int c = blockIdx.x; c < chunks; c += gridDim.x) {
    long e0 = (long)c << 8;
    int e = (int)e0 + threadIdx.x;
    float v[6] = {0.f, 0.f, 0.f, 0.f, 0.f, 0.f};
    if (e < E) {
      uint2 sd = sorted2[e];
      int s = (int)sd.x, d = (int)sd.y;
      float p0 = pos[3 * s + 0], p1 = pos[3 * s + 1], p2 = pos[3 * s + 2];
      float q0 = pos[3 * d + 0], q1 = pos[3 * d + 1], q2 = pos[3 * d + 2];
      v[0] = (p0 - q0) * invn;
      v[1] = (p1 - q1) * invn;
      v[2] = (p2 - q2) * invn;
      v[3] = x[3 * d + 0];
      v[4] = x[3 * d + 1];
      v[5] = x[3 * d + 2];
    }
    __syncthreads();  // prior MFMA phase done: stage + in6 reusable
#pragma unroll
    for (int k = 0; k < 6; k++) in6[k][threadIdx.x] = v[k];
    __syncthreads();
    int lim = E - (int)e0;
    if (lim > 256) lim = 256;
    // phase B: h1 -> swizzled LDS stage (zero-fill tail rows)
#pragma unroll
    for (int i = 0; i < 8; i++) {
      int el = wv * 64 + i * 8 + eslot;
      u32 pk[4] = {0u, 0u, 0u, 0u};
      if (el < lim) {
        float inr[6];
#pragma unroll
        for (int k = 0; k < 6; k++) inr[k] = in6[k][el];
#pragma unroll
        for (int p = 0; p < 4; p++) {
          float a0f = b1s[c0 + 2 * p];
          float a1f = b1s[c0 + 2 * p + 1];
#pragma unroll
          for (int k = 0; k < 6; k++) {
            a0f = fmaf(inr[k], w1s[k * 64 + c0 + 2 * p], a0f);
            a1f = fmaf(inr[k], w1s[k * 64 + c0 + 2 * p + 1], a1f);
          }
          u16 lo = f2bf(fmaxf(a0f, 0.f));
          u16 hi = f2bf(fmaxf(a1f, 0.f));
          pk[p] = (u32)lo | ((u32)hi << 16);
        }
      }
      int sl = (lane & 7) ^ (el & 7);
      *(uint4*)(stage + el * 64 + sl * 8) = make_uint4(pk[0], pk[1], pk[2], pk[3]);
    }
    __syncthreads();  // stage ready
    // MFMA phase: 16 tiles/chunk, wave wv owns tiles wv*4..wv*4+3
#pragma unroll
    for (int tt = 0; tt < 4; tt++) {
      int tl = wv * 4 + tt;
      int el2 = tl * 16 + m;
      const u16* rp = stage + el2 * 64;
      short8 a0 = *(const short8*)(rp + ((q ^ (m & 7)) << 3));
      short8 a1 = *(const short8*)(rp + (((4 + q) ^ (m & 7)) << 3));
      floatx4 acc[4];
#pragma unroll
      for (int t = 0; t < 4; t++) acc[t] = (floatx4){0.f, 0.f, 0.f, 0.f};
#pragma unroll
      for (int t = 0; t < 4; t++)
        acc[t] = __builtin_amdgcn_mfma_f32_16x16x32_bf16(a0, bf[t][0], acc[t], 0, 0, 0);
#pragma unroll
      for (int t = 0; t < 4; t++)
        acc[t] = __builtin_amdgcn_mfma_f32_16x16x32_bf16(a1, bf[t][1], acc[t], 0, 0, 0);
#pragma unroll
      for (int t = 0; t < 4; t++) {
#pragma unroll
        for (int r = 0; r < 4; r++) {
          int er = tl * 16 + q * 4 + r;
          if (er < lim) {
            float vv = acc[t][r] + bias2[t];
            vv = fmaxf(vv, 0.f);
            u16 hb = f2bf(vv);
            h[(e0 + er) * 64 + t * 16 + m] = hb;
            float hf = bf2f(hb);
            psum[t] += hf;
            psq[t] = fmaf(hf, hf, psq[t]);
          }
        }
      }
    }
  }

#pragma unroll
  for (int t = 0; t < 4; t++) {
    psum[t] += __shfl_xor(psum[t], 16, 64);
    psum[t] += __shfl_xor(psum[t], 32, 64);
    psq[t] += __shfl_xor(psq[t], 16, 64);
    psq[t] += __shfl_xor(psq[t], 32, 64);
  }
  if (threadIdx.x < 64) { ssum[threadIdx.x] = 0.f; ssq[threadIdx.x] = 0.f; }
  __syncthreads();
  if (q == 0) {
#pragma unroll
    for (int t = 0; t < 4; t++) {
      atomicAdd(&ssum[t * 16 + m], psum[t]);
      atomicAdd(&ssq[t * 16 + m], psq[t]);
    }
  }
  __syncthreads();
  if (threadIdx.x < 64) {
    atomicAdd(&gsum[threadIdx.x], ssum[threadIdx.x]);
    atomicAdd(&gsq[threadIdx.x], ssq[threadIdx.x]);
  }
}

// ---------------------------------------------------------------------------
// layer 1 (FALLBACK PATH ONLY), two-phase, writes h.
__global__ __launch_bounds__(256) void k_layer1(
    const int* __restrict__ ei, const float* __restrict__ pos,
    const float* __restrict__ x, const float* __restrict__ W1,
    const float* __restrict__ b1, u16* __restrict__ h,
    const float* __restrict__ stats, float* __restrict__ gsum,
    float* __restrict__ gsq, int E, const uint2* __restrict__ sorted2) {
  __shared__ float in6[6][256];
  __shared__ float ssum[64], ssq[64];
  float invn = 1.0f / sqrtf(stats[0]);
  int t = threadIdx.x;
  int lane = t & 63;
  int wv = t >> 6;
  int eslot = lane >> 3;
  int c0 = (lane & 7) * 8;
  float w[6][8];
#pragma unroll
  for (int k = 0; k < 6; k++)
#pragma unroll
    for (int j = 0; j < 8; j++) w[k][j] = W1[k * 64 + c0 + j];
  float bias[8];
#pragma unroll
  for (int j = 0; j < 8; j++) bias[j] = b1[c0 + j];
  float psum[8] = {0.f, 0.f, 0.f, 0.f, 0.f, 0.f, 0.f, 0.f};
  float psq[8] = {0.f, 0.f, 0.f, 0.f, 0.f, 0.f, 0.f, 0.f};

  int chunks = (E + 255) >> 8;
  for (int c = blockIdx.x; c < chunks; c += gridDim.x) {
    long e0 = (long)c << 8;
    int e = (int)e0 + t;
    float v[6] = {0.f, 0.f, 0.f, 0.f, 0.f, 0.f};
    if (e < E) {
      int s, d;
      if (sorted2) {
        uint2 sd = sorted2[e];
        s = (int)sd.x;
        d = (int)sd.y;
      } else {
        s = ei[e];
        d = ei[E + e];
      }
      float p0 = pos[3 * s + 0], p1 = pos[3 * s + 1], p2 = pos[3 * s + 2];
      float q0 = pos[3 * d + 0], q1 = pos[3 * d + 1], q2 = pos[3 * d + 2];
      v[0] = (p0 - q0) * invn;
      v[1] = (p1 - q1) * invn;
      v[2] = (p2 - q2) * invn;
      v[3] = x[3 * d + 0];
      v[4] = x[3 * d + 1];
      v[5] = x[3 * d + 2];
    }
    __syncthreads();
#pragma unroll
    for (int k = 0; k < 6; k++) in6[k][t] = v[k];
    __syncthreads();
    int lim = E - (int)e0;
    if (lim > 256) lim = 256;
#pragma unroll
    for (int i = 0; i < 8; i++) {
      int el = wv * 64 + i * 8 + eslot;
      if (el >= lim) continue;
      float hv[8];
#pragma unroll
      for (int j = 0; j < 8; j++) {
        float acc = bias[j];
#pragma unroll
        for (int k = 0; k < 6; k++) acc = fmaf(in6[k][el], w[k][j], acc);
        hv[j] = fmaxf(acc, 0.f);
      }
      u32 pk[4];
#pragma unroll
      for (int p = 0; p < 4; p++) {
        u16 lo = f2bf(hv[2 * p]);
        u16 hi = f2bf(hv[2 * p + 1]);
        pk[p] = (u32)lo | ((u32)hi << 16);
        float f0 = bf2f(lo), f1 = bf2f(hi);
        psum[2 * p] += f0;
        psq[2 * p] = fmaf(f0, f0, psq[2 * p]);
        psum[2 * p + 1] += f1;
        psq[2 * p + 1] = fmaf(f1, f1, psq[2 * p + 1]);
      }
      *(uint4*)(h + (e0 + el) * 64 + c0) = make_uint4(pk[0], pk[1], pk[2], pk[3]);
    }
  }
  if (t < 64) { ssum[t] = 0.f; ssq[t] = 0.f; }
  __syncthreads();
#pragma unroll
  for (int j = 0; j < 8; j++) {
    atomicAdd(&ssum[c0 + j], psum[j]);
    atomicAdd(&ssq[c0 + j], psq[j]);
  }
  __syncthreads();
  if (t < 64) {
    atomicAdd(&gsum[t], ssum[t]);
    atomicAdd(&gsq[t], ssq[t]);
  }
}

// ---------------------------------------------------------------------------
// layer 3 (and fallback layer 2): h = relu( bn_in(h) @ W + b ), in place.
// Non-swap body, VGPR 56.
__global__ __launch_bounds__(256) void k_layer_mfma(
    u16* h, const float* __restrict__ W, const float* __restrict__ b,
    const float* __restrict__ gsum_in, const float* __restrict__ gsq_in,
    const float* __restrict__ g_in, const float* __restrict__ be_in, float invE,
    float* __restrict__ gsum, float* __restrict__ gsq, int E) {
  __shared__ float sc_s[64], sh_s[64];
  if (threadIdx.x < 64) {
    int c = threadIdx.x;
    float mu = gsum_in[c] * invE;
    float var = gsq_in[c] * invE - mu * mu;
    float s = g_in[c] * rsqrtf(var + BN_EPS);
    sc_s[c] = s;
    sh_s[c] = be_in[c] - mu * s;
  }
  __syncthreads();

  int lane = threadIdx.x & 63;
  int m = lane & 15;
  int q = lane >> 4;

  short8 bf[4][2];
  float bias[4];
#pragma unroll
  for (int t = 0; t < 4; t++) {
    int n = t * 16 + m;
    float bb = b[n];
    for (int k = 0; k < 64; k++) bb = fmaf(sh_s[k], W[k * 64 + n], bb);
    bias[t] = bb;
#pragma unroll
    for (int s = 0; s < 2; s++)
#pragma unroll
      for (int j = 0; j < 8; j++) {
        int k = s * 32 + q * 8 + j;
        bf[t][s][j] = (short)f2bf(W[k * 64 + n] * sc_s[k]);
      }
  }

  float psum[4] = {0.f, 0.f, 0.f, 0.f}, psq[4] = {0.f, 0.f, 0.f, 0.f};

  int tiles = E >> 4;
  int gw = ((int)blockIdx.x * (blockDim.x >> 6)) + (threadIdx.x >> 6);
  int nw = (int)gridDim.x * (blockDim.x >> 6);

  for (int tile = gw; tile < tiles; tile += nw) {
    long e0 = (long)tile * 16;
    const u16* rowp = h + (e0 + m) * 64 + q * 8;
    short8 a0 = *(const short8*)(rowp);
    short8 a1 = *(const short8*)(rowp + 32);
    floatx4 acc[4];
#pragma unroll
    for (int t = 0; t < 4; t++) acc[t] = (floatx4){0.f, 0.f, 0.f, 0.f};
#pragma unroll
    for (int t = 0; t < 4; t++)
      acc[t] = __builtin_amdgcn_mfma_f32_16x16x32_bf16(a0, bf[t][0], acc[t], 0, 0, 0);
#pragma unroll
    for (int t = 0; t < 4; t++)
      acc[t] = __builtin_amdgcn_mfma_f32_16x16x32_bf16(a1, bf[t][1], acc[t], 0, 0, 0);

#pragma unroll
    for (int t = 0; t < 4; t++) {
#pragma unroll
      for (int r = 0; r < 4; r++) {
        float v = acc[t][r] + bias[t];
        v = fmaxf(v, 0.f);
        u16 hb = f2bf(v);
        h[(e0 + q * 4 + r) * 64 + t * 16 + m] = hb;
        float hf = bf2f(hb);
        psum[t] += hf;
        psq[t] = fmaf(hf, hf, psq[t]);
      }
    }
  }

#pragma unroll
  for (int t = 0; t < 4; t++) {
    psum[t] += __shfl_xor(psum[t], 16, 64);
    psum[t] += __shfl_xor(psum[t], 32, 64);
    psq[t] += __shfl_xor(psq[t], 16, 64);
    psq[t] += __shfl_xor(psq[t], 32, 64);
  }
  __shared__ float ssum[64], ssq[64];
  if (threadIdx.x < 64) { ssum[threadIdx.x] = 0.f; ssq[threadIdx.x] = 0.f; }
  __syncthreads();
  if (q == 0) {
#pragma unroll
    for (int t = 0; t < 4; t++) {
      atomicAdd(&ssum[t * 16 + m], psum[t]);
      atomicAdd(&ssq[t * 16 + m], psq[t]);
    }
  }
  __syncthreads();
  if (threadIdx.x < 64) {
    atomicAdd(&gsum[threadIdx.x], ssum[threadIdx.x]);
    atomicAdd(&gsq[threadIdx.x], ssq[threadIdx.x]);
  }
}

// ---------------------------------------------------------------------------
// per-bucket scatter-max in LDS, STREAMING (unchanged from best config).
__global__ __launch_bounds__(256) void k_bucket_max(
    const u8* __restrict__ ln8, const u32* __restrict__ base,
    const u16* __restrict__ h, const float* __restrict__ gsum3,
    const float* __restrict__ gsq3, const float* __restrict__ g3,
    const float* __restrict__ be3, float invE, float* __restrict__ outf, int N) {
  __shared__ u32 tile[NPB * 64];  // 16 KB of keys; 0 == empty
  for (int i = threadIdx.x; i < NPB * 64; i += blockDim.x) tile[i] = 0u;
  int b = blockIdx.x;
  u32 start = base[b];
  int cnt = (int)(base[b + 1] - start);
  int t = threadIdx.x;
  int es = t >> 3;       // edge slot 0..31
  int c0 = (t & 7) * 8;  // this thread's 8 channels
  u32 mm[4];             // per-channel-pair xor masks (0xFFFF where gamma<0)
#pragma unroll
  for (int p = 0; p < 4; p++) {
    u32 m0 = (g3[c0 + 2 * p] < 0.f) ? 0xFFFFu : 0u;
    u32 m1 = (g3[c0 + 2 * p + 1] < 0.f) ? 0xFFFFu : 0u;
    mm[p] = m0 | (m1 << 16);
  }
  __syncthreads();

  for (int i0 = 0; i0 < cnt; i0 += 128) {  // 32 edges x 4-deep unroll
    uint4 raw[4];
    u32 ln[4];
    int ok[4];
#pragma unroll
    for (int u_ = 0; u_ < 4; u_++) {
      int sl = i0 + u_ * 32 + es;
      ok[u_] = sl < cnt;
      if (ok[u_]) {
        ln[u_] = (u32)ln8[start + sl];
        raw[u_] = *(const uint4*)(h + (long)(start + sl) * 64 + c0);
      }
    }
#pragma unroll
    for (int u_ = 0; u_ < 4; u_++) {
      if (!ok[u_]) continue;
      unsigned w[4] = {raw[u_].x, raw[u_].y, raw[u_].z, raw[u_].w};
      u32 key[8];
#pragma unroll
      for (int p = 0; p < 4; p++) {
        u32 wx = w[p] ^ mm[p];
        key[2 * p] = (wx & 0xFFFFu) | 0x10000u;
        key[2 * p + 1] = (wx >> 16) | 0x10000u;
      }
      u32 baseA = ln[u_] * 64u + (u32)c0;
#pragma unroll
      for (int jj = 0; jj < 8; jj++) {
        int j = (jj + es) & 7;
        atomicMax(&tile[baseA + j], key[j]);
      }
    }
  }
  __syncthreads();
  int c = t & 63;
  float mu = gsum3[c] * invE;
  float var = gsq3[c] * invE - mu * mu;
  float sc = g3[c] * rsqrtf(var + BN_EPS);
  float sh = be3[c] - mu * sc;
  u32 me = (g3[c] < 0.f) ? 0xFFFFu : 0u;
  int node0 = b * NPB;
  for (int l = t; l < NPB * 64; l += blockDim.x) {
    int node = node0 + (l >> 6);
    if (node < N) {
      u32 k = tile[l];
      float v = (k == 0u) ? 0.f : fmaf(bf2f((u16)((k & 0xFFFFu) ^ me)), sc, sh);
      outf[(long)node * 64 + (l & 63)] = v;
    }
  }
}

// ---------------------------------------------------------------------------
// fallback path kernels (only if ws too small): -inf init, atomic scatter, fixup
__global__ void k_initout(float* __restrict__ outf, long n, float* __restrict__ stats,
                          u32* __restrict__ bucketTotal) {
  long i = (long)blockIdx.x * blockDim.x + threadIdx.x;
  long stride = (long)gridDim.x * blockDim.x;
  for (long j = i; j < n; j += stride) outf[j] = __uint_as_float(0xFF800000u);
  if (i < 1024) stats[i] = 0.f;
  if (i < NBMAX + 1) bucketTotal[i] = 0u;
}
__global__ void k_scatter(const int* __restrict__ ei, const u16* __restrict__ h,
                          const float* __restrict__ gsum3, const float* __restrict__ gsq3,
                          const float* __restrict__ g3, const float* __restrict__ be3,
                          float invE, float* outf, int E) {
  int lane = threadIdx.x & 63;
  int gw = ((int)blockIdx.x * (blockDim.x >> 6)) + (threadIdx.x >> 6);
  int nw = (int)gridDim.x * (blockDim.x >> 6);
  float mu = gsum3[lane] * invE;
  float var = gsq3[lane] * invE - mu * mu;
  float sc = g3[lane] * rsqrtf(var + BN_EPS);
  float sh = be3[lane] - mu * sc;
  for (int e = gw; e < E; e += nw) {
    int d = ei[E + e];
    float v = fmaf(bf2f(h[(long)e * 64 + lane]), sc, sh);
    float* addr = outf + (long)d * 64 + lane;
    if (v >= 0.f)
      atomicMax((int*)addr, __float_as_int(v));
    else
      atomicMin((unsigned int*)addr, __float_as_uint(v));
  }
}
__global__ void k_out(float* __restrict__ outf, long n) {
  long i = (long)blockIdx.x * blockDim.x + threadIdx.x;
  long stride = (long)gridDim.x * blockDim.x;
  for (long j = i; j < n; j += stride) {
    float v = outf[j];
    unsigned u = __float_as_uint(v);
    if ((u & 0x7F800000u) == 0x7F800000u) v = 0.f;
    outf[j] = v;
  }
}

// ---------------------------------------------------------------------------
extern "C" void kernel_launch(void* const* d_in, const int* in_sizes, int n_in,
                              void* d_out, int out_size, void* d_ws, size_t ws_size,
                              hipStream_t stream) {
  const float* x = (const float*)d_in[0];
  const float* pos = (const float*)d_in[1];
  const int* ei = (const int*)d_in[2];
  const float* W1 = (const float*)d_in[3];
  const float* b1 = (const float*)d_in[4];
  const float* g1 = (const float*)d_in[5];
  const float* be1 = (const float*)d_in[6];
  const float* W2 = (const float*)d_in[7];
  const float* b2 = (const float*)d_in[8];
  const float* g2 = (const float*)d_in[9];
  const float* be2 = (const float*)d_in[10];
  const float* W3 = (const float*)d_in[11];
  const float* b3 = (const float*)d_in[12];
  const float* g3 = (const float*)d_in[13];
  const float* be3 = (const float*)d_in[14];

  int N = in_sizes[0] / 3;
  int E = in_sizes[2] / 2;
  int NB = (N + NPB - 1) / NPB;
  long n_out = (long)N * 64;

  char* wsb = (char*)d_ws;
  u16* h = (u16*)wsb;  // [E,64] bf16 activations, in sorted-slot order
  size_t off = (size_t)E * 64 * 2;
  float* stats = (float*)(wsb + off);
  off += 1024 * 4;
  u32* bucketTotal = (u32*)(wsb + off);
  off += (NBMAX + 1) * 4;
  u32* baseArr = (u32*)(wsb + off);
  off += (NBMAX + 1) * 4;
  u32* cursor = (u32*)(wsb + off);
  off += NBMAX * 4;
  off = (off + 7) & ~(size_t)7;  // 8-align for uint2
  uint2* sorted2 = (uint2*)(wsb + off);
  off += (size_t)E * 8;
  u8* ln8 = (u8*)(wsb + off);
  off += (size_t)E;
  size_t need = off;

  float* gsum1 = stats + 64, * gsq1 = stats + 128;
  float* gsum2 = stats + 192, * gsq2 = stats + 256;
  float* gsum3 = stats + 320, * gsq3 = stats + 384;

  float* outf = (float*)d_out;
  float invE = 1.0f / (float)E;
  bool binned = (ws_size >= need) && (NB <= NBMAX);

  if (binned) {
    k_init<<<1, 1024, 0, stream>>>(stats, bucketTotal);
    k_norm_hist<<<256, 256, 0, stream>>>(ei, pos, E, NB, stats, bucketTotal);
    k_scan<<<1, 64, 0, stream>>>(bucketTotal, baseArr, cursor, NB);
    k_place<<<256, 256, 0, stream>>>(ei, E, NB, cursor, sorted2, ln8);
    k_stats1<<<1024, 256, 0, stream>>>(pos, x, W1, b1, stats, gsum1, gsq1, E, sorted2);
    k_layer12<<<768, 256, 0, stream>>>(pos, x, W1, b1, stats, sorted2, W2, b2,
                                       gsum1, gsq1, g1, be1, invE, h, gsum2, gsq2, E);
    k_layer_mfma<<<1536, 256, 0, stream>>>(h, W3, b3, gsum2, gsq2, g2, be2, invE, gsum3, gsq3, E);
    k_bucket_max<<<NB, 256, 0, stream>>>(ln8, baseArr, h, gsum3, gsq3, g3, be3, invE, outf, N);
  } else {
    k_initout<<<4096, 256, 0, stream>>>(outf, n_out, stats, bucketTotal);
    k_norm_hist<<<256, 256, 0, stream>>>(ei, pos, E, NB <= NBMAX ? NB : 1, stats, bucketTotal);
    k_layer1<<<1024, 256, 0, stream>>>(ei, pos, x, W1, b1, h, stats, gsum1, gsq1, E, (const uint2*)nullptr);
    k_layer_mfma<<<2048, 256, 0, stream>>>(h, W2, b2, gsum1, gsq1, g1, be1, invE, gsum2, gsq2, E);
    k_layer_mfma<<<2048, 256, 0, stream>>>(h, W3, b3, gsum2, gsq2, g2, be2, invE, gsum3, gsq3, E);
    k_scatter<<<2048, 256, 0, stream>>>(ei, h, gsum3, gsq3, g3, be3, invE, outf, E);
    k_out<<<2048, 256, 0, stream>>>(outf, n_out);
  }
}

// Round 13
// 478.660 us; speedup vs baseline: 1.0758x; 1.0758x over previous
//
#include <hip/hip_runtime.h>
#include <stdint.h>

typedef unsigned char u8;
typedef unsigned short u16;
typedef unsigned int u32;
typedef __attribute__((ext_vector_type(8))) short short8;
typedef __attribute__((ext_vector_type(4))) float floatx4;

#define BN_EPS 1e-5f
#define NPB 64        // nodes per bucket (power of 2; bucket = dst >> NPB_SHIFT)
#define NPB_SHIFT 6
#define NBMAX 2048

__device__ __forceinline__ float bf2f(u16 u) { return __uint_as_float(((unsigned)u) << 16); }
__device__ __forceinline__ u16 f2bf(float f) {
  unsigned u = __float_as_uint(f);
  u += 0x7FFFu + ((u >> 16) & 1u);   // round-to-nearest-even
  return (u16)(u >> 16);
}

// ---------------------------------------------------------------------------
// zero the small control block (stats + bucket totals)
__global__ void k_init(float* __restrict__ stats, u32* __restrict__ bucketTotal) {
  for (int i = threadIdx.x; i < 1024; i += blockDim.x) stats[i] = 0.f;
  for (int i = threadIdx.x; i < NBMAX + 1; i += blockDim.x) bucketTotal[i] = 0u;
}

// ---------------------------------------------------------------------------
// fused: global sum-of-squares of directions + per-bucket dst histogram
__global__ void k_norm_hist(const int* __restrict__ ei, const float* __restrict__ pos,
                            int E, int NB, float* __restrict__ stats,
                            u32* __restrict__ bucketTotal) {
  __shared__ u32 lh[NBMAX];
  __shared__ float red[16];
  for (int i = threadIdx.x; i < NB; i += blockDim.x) lh[i] = 0u;
  __syncthreads();
  int tid = blockIdx.x * blockDim.x + threadIdx.x;
  int stride = gridDim.x * blockDim.x;
  float acc = 0.f;
  for (int e = tid; e < E; e += stride) {
    int s = ei[e], d = ei[E + e];
    float d0 = pos[3 * s + 0] - pos[3 * d + 0];
    float d1 = pos[3 * s + 1] - pos[3 * d + 1];
    float d2 = pos[3 * s + 2] - pos[3 * d + 2];
    acc = fmaf(d0, d0, acc);
    acc = fmaf(d1, d1, acc);
    acc = fmaf(d2, d2, acc);
    atomicAdd(&lh[d >> NPB_SHIFT], 1u);
  }
#pragma unroll
  for (int off = 32; off > 0; off >>= 1) acc += __shfl_down(acc, off, 64);
  if ((threadIdx.x & 63) == 0) red[threadIdx.x >> 6] = acc;
  __syncthreads();
  if (threadIdx.x == 0) {
    float s = 0.f;
    for (int w = 0; w < (int)(blockDim.x >> 6); w++) s += red[w];
    atomicAdd(&stats[0], s);
  }
  for (int i = threadIdx.x; i < NB; i += blockDim.x)
    if (lh[i]) atomicAdd(&bucketTotal[i], lh[i]);
}

// ---------------------------------------------------------------------------
// exclusive scan of bucket totals — single wave, shfl prefix scan
__global__ void k_scan(const u32* __restrict__ bucketTotal, u32* __restrict__ base,
                       u32* __restrict__ cursor, int NB) {
  int lane = threadIdx.x;  // launched with 64 threads, 1 block
  u32 run = 0;
  for (int b0 = 0; b0 < NB; b0 += 64) {
    int b = b0 + lane;
    u32 v = (b < NB) ? bucketTotal[b] : 0u;
    u32 s = v;
#pragma unroll
    for (int off = 1; off < 64; off <<= 1) {
      u32 t = __shfl_up(s, off, 64);
      if (lane >= off) s += t;
    }
    u32 excl = run + s - v;
    if (b < NB) { base[b] = excl; cursor[b] = excl; }
    run += __shfl(s, 63, 64);   // broadcast chunk total
  }
  if (lane == 0) base[NB] = run;
}

// ---------------------------------------------------------------------------
// bin edges by dst bucket: sorted2[slot] = {src, dst} (coalesced-consumable
// by layer1) + ln8[slot] = dst & 63 (compact lane id for bucket_max).
__global__ void k_place(const int* __restrict__ ei, int E, int NB,
                        u32* __restrict__ cursor, uint2* __restrict__ sorted2,
                        u8* __restrict__ ln8) {
  __shared__ u32 lh[NBMAX];
  __shared__ u32 lbase[NBMAX];
  for (int i = threadIdx.x; i < NB; i += blockDim.x) lh[i] = 0u;
  __syncthreads();
  int tid = blockIdx.x * blockDim.x + threadIdx.x;
  int stride = gridDim.x * blockDim.x;
  for (int e = tid; e < E; e += stride) atomicAdd(&lh[ei[E + e] >> NPB_SHIFT], 1u);
  __syncthreads();
  for (int i = threadIdx.x; i < NB; i += blockDim.x) {
    u32 c = lh[i];
    lbase[i] = c ? atomicAdd(&cursor[i], c) : 0u;
    lh[i] = 0u;
  }
  __syncthreads();
  for (int e = tid; e < E; e += stride) {
    int s = ei[e];
    int d = ei[E + e];
    int b = d >> NPB_SHIFT;
    u32 slot = lbase[b] + atomicAdd(&lh[b], 1u);
    sorted2[slot] = make_uint2((u32)s, (u32)d);
    ln8[slot] = (u8)(d & (NPB - 1));
  }
}

// ---------------------------------------------------------------------------
// layer 1, two-phase, slot-ordered. Phase A: 256 parallel gathers -> LDS
// (sorted2 coalesced; pos/x L2-resident). Phase B: each thread owns 8
// channels x 8 edges -> one uint4 (16B) store per edge segment; wave writes
// 1 KB contiguous; 8x fewer LDS reads and store instructions.
__global__ __launch_bounds__(256) void k_layer1(
    const int* __restrict__ ei, const float* __restrict__ pos,
    const float* __restrict__ x, const float* __restrict__ W1,
    const float* __restrict__ b1, u16* __restrict__ h,
    const float* __restrict__ stats, float* __restrict__ gsum,
    float* __restrict__ gsq, int E, const uint2* __restrict__ sorted2) {
  __shared__ float in6[6][256];
  __shared__ float ssum[64], ssq[64];
  float invn = 1.0f / sqrtf(stats[0]);
  int t = threadIdx.x;
  int lane = t & 63;
  int wv = t >> 6;         // wave 0..3: edges [wv*64, wv*64+64) of the chunk
  int eslot = lane >> 3;   // 0..7
  int c0 = (lane & 7) * 8; // this thread's 8 channels
  float w[6][8];
#pragma unroll
  for (int k = 0; k < 6; k++)
#pragma unroll
    for (int j = 0; j < 8; j++) w[k][j] = W1[k * 64 + c0 + j];
  float bias[8];
#pragma unroll
  for (int j = 0; j < 8; j++) bias[j] = b1[c0 + j];
  float psum[8] = {0.f, 0.f, 0.f, 0.f, 0.f, 0.f, 0.f, 0.f};
  float psq[8] = {0.f, 0.f, 0.f, 0.f, 0.f, 0.f, 0.f, 0.f};

  int chunks = (E + 255) >> 8;
  for (int c = blockIdx.x; c < chunks; c += gridDim.x) {
    long e0 = (long)c << 8;
    int e = (int)e0 + t;   // slot id (phase A: one edge per thread)
    float v[6] = {0.f, 0.f, 0.f, 0.f, 0.f, 0.f};
    if (e < E) {
      int s, d;
      if (sorted2) {
        uint2 sd = sorted2[e];
        s = (int)sd.x;
        d = (int)sd.y;
      } else {
        s = ei[e];
        d = ei[E + e];
      }
      float p0 = pos[3 * s + 0], p1 = pos[3 * s + 1], p2 = pos[3 * s + 2];
      float q0 = pos[3 * d + 0], q1 = pos[3 * d + 1], q2 = pos[3 * d + 2];
      v[0] = (p0 - q0) * invn;
      v[1] = (p1 - q1) * invn;
      v[2] = (p2 - q2) * invn;
      v[3] = x[3 * d + 0];
      v[4] = x[3 * d + 1];
      v[5] = x[3 * d + 2];
    }
    __syncthreads();  // previous chunk's phase-B reads done
#pragma unroll
    for (int k = 0; k < 6; k++) in6[k][t] = v[k];
    __syncthreads();
    int lim = E - (int)e0;
    if (lim > 256) lim = 256;
#pragma unroll
    for (int i = 0; i < 8; i++) {
      int el = wv * 64 + i * 8 + eslot;  // 8 consecutive rows per wave-iter
      if (el >= lim) continue;
      float hv[8];
#pragma unroll
      for (int j = 0; j < 8; j++) {
        float acc = bias[j];
#pragma unroll
        for (int k = 0; k < 6; k++) acc = fmaf(in6[k][el], w[k][j], acc);
        hv[j] = fmaxf(acc, 0.f);
      }
      u32 pk[4];
#pragma unroll
      for (int p = 0; p < 4; p++) {
        u16 lo = f2bf(hv[2 * p]);
        u16 hi = f2bf(hv[2 * p + 1]);
        pk[p] = (u32)lo | ((u32)hi << 16);
        float f0 = bf2f(lo), f1 = bf2f(hi);
        psum[2 * p] += f0;
        psq[2 * p] = fmaf(f0, f0, psq[2 * p]);
        psum[2 * p + 1] += f1;
        psq[2 * p + 1] = fmaf(f1, f1, psq[2 * p + 1]);
      }
      *(uint4*)(h + (e0 + el) * 64 + c0) = make_uint4(pk[0], pk[1], pk[2], pk[3]);
    }
  }
  if (t < 64) { ssum[t] = 0.f; ssq[t] = 0.f; }
  __syncthreads();
#pragma unroll
  for (int j = 0; j < 8; j++) {
    atomicAdd(&ssum[c0 + j], psum[j]);
    atomicAdd(&ssq[c0 + j], psq[j]);
  }
  __syncthreads();
  if (t < 64) {
    atomicAdd(&gsum[t], ssum[t]);
    atomicAdd(&gsq[t], ssq[t]);
  }
}

// ---------------------------------------------------------------------------
// layers 2/3: h = relu( bn_in(h) @ W + b ), in place. BN finalize computed in
// a 64-thread prologue from gsum/gsq, folded into W' = sc_in*W and
// bias' = b + sh_in^T W, so A-frags are RAW uint4 loads. VGPR 56 (< 64
// cliff); grid 1536 = 6 blocks/CU (best measured config: r7, 94 us).
__global__ __launch_bounds__(256) void k_layer_mfma(
    u16* h, const float* __restrict__ W, const float* __restrict__ b,
    const float* __restrict__ gsum_in, const float* __restrict__ gsq_in,
    const float* __restrict__ g_in, const float* __restrict__ be_in, float invE,
    float* __restrict__ gsum, float* __restrict__ gsq, int E) {
  __shared__ float sc_s[64], sh_s[64];
  if (threadIdx.x < 64) {
    int c = threadIdx.x;
    float mu = gsum_in[c] * invE;
    float var = gsq_in[c] * invE - mu * mu;
    float s = g_in[c] * rsqrtf(var + BN_EPS);
    sc_s[c] = s;
    sh_s[c] = be_in[c] - mu * s;
  }
  __syncthreads();

  int lane = threadIdx.x & 63;
  int m = lane & 15;
  int q = lane >> 4;

  short8 bf[4][2];
  float bias[4];
#pragma unroll
  for (int t = 0; t < 4; t++) {
    int n = t * 16 + m;
    float bb = b[n];
    for (int k = 0; k < 64; k++) bb = fmaf(sh_s[k], W[k * 64 + n], bb);
    bias[t] = bb;
#pragma unroll
    for (int s = 0; s < 2; s++)
#pragma unroll
      for (int j = 0; j < 8; j++) {
        int k = s * 32 + q * 8 + j;
        bf[t][s][j] = (short)f2bf(W[k * 64 + n] * sc_s[k]);
      }
  }

  float psum[4] = {0.f, 0.f, 0.f, 0.f}, psq[4] = {0.f, 0.f, 0.f, 0.f};

  int tiles = E >> 4;
  int gw = ((int)blockIdx.x * (blockDim.x >> 6)) + (threadIdx.x >> 6);
  int nw = (int)gridDim.x * (blockDim.x >> 6);

  for (int tile = gw; tile < tiles; tile += nw) {
    long e0 = (long)tile * 16;
    const u16* rowp = h + (e0 + m) * 64 + q * 8;
    short8 a0 = *(const short8*)(rowp);
    short8 a1 = *(const short8*)(rowp + 32);
    floatx4 acc[4];
#pragma unroll
    for (int t = 0; t < 4; t++) acc[t] = (floatx4){0.f, 0.f, 0.f, 0.f};
#pragma unroll
    for (int t = 0; t < 4; t++)
      acc[t] = __builtin_amdgcn_mfma_f32_16x16x32_bf16(a0, bf[t][0], acc[t], 0, 0, 0);
#pragma unroll
    for (int t = 0; t < 4; t++)
      acc[t] = __builtin_amdgcn_mfma_f32_16x16x32_bf16(a1, bf[t][1], acc[t], 0, 0, 0);

#pragma unroll
    for (int t = 0; t < 4; t++) {
#pragma unroll
      for (int r = 0; r < 4; r++) {
        float v = acc[t][r] + bias[t];
        v = fmaxf(v, 0.f);
        u16 hb = f2bf(v);
        h[(e0 + q * 4 + r) * 64 + t * 16 + m] = hb;
        float hf = bf2f(hb);
        psum[t] += hf;
        psq[t] = fmaf(hf, hf, psq[t]);
      }
    }
  }

#pragma unroll
  for (int t = 0; t < 4; t++) {
    psum[t] += __shfl_xor(psum[t], 16, 64);
    psum[t] += __shfl_xor(psum[t], 32, 64);
    psq[t] += __shfl_xor(psq[t], 16, 64);
    psq[t] += __shfl_xor(psq[t], 32, 64);
  }
  __shared__ float ssum[64], ssq[64];
  if (threadIdx.x < 64) { ssum[threadIdx.x] = 0.f; ssq[threadIdx.x] = 0.f; }
  __syncthreads();
  if (q == 0) {
#pragma unroll
    for (int t = 0; t < 4; t++) {
      atomicAdd(&ssum[t * 16 + m], psum[t]);
      atomicAdd(&ssq[t * 16 + m], psq[t]);
    }
  }
  __syncthreads();
  if (threadIdx.x < 64) {
    atomicAdd(&gsum[threadIdx.x], ssum[threadIdx.x]);
    atomicAdd(&gsq[threadIdx.x], ssq[threadIdx.x]);
  }
}

// ---------------------------------------------------------------------------
// per-bucket scatter-max in LDS, STREAMING: h is in sorted-slot order, so
// each block reads a contiguous [base[b],base[b+1]) range of h (coalesced
// 1 KB/wave-load) plus 1 byte/edge of lane ids. Max on raw bf16 bit-patterns
// (relu out >= 0 -> unsigned-ordered; per-channel XOR mask handles gamma<0),
// bit16 = non-empty marker. BN3 applied once per node-channel in epilogue.
__global__ __launch_bounds__(256) void k_bucket_max(
    const u8* __restrict__ ln8, const u32* __restrict__ base,
    const u16* __restrict__ h, const float* __restrict__ gsum3,
    const float* __restrict__ gsq3, const float* __restrict__ g3,
    const float* __restrict__ be3, float invE, float* __restrict__ outf, int N) {
  __shared__ u32 tile[NPB * 64];  // 16 KB of keys; 0 == empty
  for (int i = threadIdx.x; i < NPB * 64; i += blockDim.x) tile[i] = 0u;
  int b = blockIdx.x;
  u32 start = base[b];
  int cnt = (int)(base[b + 1] - start);
  int t = threadIdx.x;
  int es = t >> 3;       // edge slot 0..31
  int c0 = (t & 7) * 8;  // this thread's 8 channels
  u32 mm[4];             // per-channel-pair xor masks (0xFFFF where gamma<0)
#pragma unroll
  for (int p = 0; p < 4; p++) {
    u32 m0 = (g3[c0 + 2 * p] < 0.f) ? 0xFFFFu : 0u;
    u32 m1 = (g3[c0 + 2 * p + 1] < 0.f) ? 0xFFFFu : 0u;
    mm[p] = m0 | (m1 << 16);
  }
  __syncthreads();

  for (int i0 = 0; i0 < cnt; i0 += 128) {  // 32 edges x 4-deep unroll
    uint4 raw[4];
    u32 ln[4];
    int ok[4];
#pragma unroll
    for (int u_ = 0; u_ < 4; u_++) {
      int sl = i0 + u_ * 32 + es;
      ok[u_] = sl < cnt;
      if (ok[u_]) {
        ln[u_] = (u32)ln8[start + sl];
        raw[u_] = *(const uint4*)(h + (long)(start + sl) * 64 + c0);
      }
    }
#pragma unroll
    for (int u_ = 0; u_ < 4; u_++) {
      if (!ok[u_]) continue;
      unsigned w[4] = {raw[u_].x, raw[u_].y, raw[u_].z, raw[u_].w};
      u32 key[8];
#pragma unroll
      for (int p = 0; p < 4; p++) {
        u32 wx = w[p] ^ mm[p];
        key[2 * p] = (wx & 0xFFFFu) | 0x10000u;
        key[2 * p + 1] = (wx >> 16) | 0x10000u;
      }
      u32 baseA = ln[u_] * 64u + (u32)c0;
      // per-edge-slot rotated channel order -> 2 lanes/bank (min for wave64)
#pragma unroll
      for (int jj = 0; jj < 8; jj++) {
        int j = (jj + es) & 7;
        atomicMax(&tile[baseA + j], key[j]);
      }
    }
  }
  __syncthreads();
  // epilogue: stride-256 means channel c = t&63 is fixed per thread
  int c = t & 63;
  float mu = gsum3[c] * invE;
  float var = gsq3[c] * invE - mu * mu;
  float sc = g3[c] * rsqrtf(var + BN_EPS);
  float sh = be3[c] - mu * sc;
  u32 me = (g3[c] < 0.f) ? 0xFFFFu : 0u;
  int node0 = b * NPB;
  for (int l = t; l < NPB * 64; l += blockDim.x) {
    int node = node0 + (l >> 6);
    if (node < N) {
      u32 k = tile[l];
      float v = (k == 0u) ? 0.f : fmaf(bf2f((u16)((k & 0xFFFFu) ^ me)), sc, sh);
      outf[(long)node * 64 + (l & 63)] = v;
    }
  }
}

// ---------------------------------------------------------------------------
// fallback path kernels (only if ws too small): -inf init, atomic scatter, fixup
__global__ void k_initout(float* __restrict__ outf, long n, float* __restrict__ stats,
                          u32* __restrict__ bucketTotal) {
  long i = (long)blockIdx.x * blockDim.x + threadIdx.x;
  long stride = (long)gridDim.x * blockDim.x;
  for (long j = i; j < n; j += stride) outf[j] = __uint_as_float(0xFF800000u);
  if (i < 1024) stats[i] = 0.f;
  if (i < NBMAX + 1) bucketTotal[i] = 0u;
}
__global__ void k_scatter(const int* __restrict__ ei, const u16* __restrict__ h,
                          const float* __restrict__ gsum3, const float* __restrict__ gsq3,
                          const float* __restrict__ g3, const float* __restrict__ be3,
                          float invE, float* outf, int E) {
  int lane = threadIdx.x & 63;
  int gw = ((int)blockIdx.x * (blockDim.x >> 6)) + (threadIdx.x >> 6);
  int nw = (int)gridDim.x * (blockDim.x >> 6);
  float mu = gsum3[lane] * invE;
  float var = gsq3[lane] * invE - mu * mu;
  float sc = g3[lane] * rsqrtf(var + BN_EPS);
  float sh = be3[lane] - mu * sc;
  for (int e = gw; e < E; e += nw) {
    int d = ei[E + e];
    float v = fmaf(bf2f(h[(long)e * 64 + lane]), sc, sh);
    float* addr = outf + (long)d * 64 + lane;
    if (v >= 0.f)
      atomicMax((int*)addr, __float_as_int(v));
    else
      atomicMin((unsigned int*)addr, __float_as_uint(v));
  }
}
__global__ void k_out(float* __restrict__ outf, long n) {
  long i = (long)blockIdx.x * blockDim.x + threadIdx.x;
  long stride = (long)gridDim.x * blockDim.x;
  for (long j = i; j < n; j += stride) {
    float v = outf[j];
    unsigned u = __float_as_uint(v);
    if ((u & 0x7F800000u) == 0x7F800000u) v = 0.f;
    outf[j] = v;
  }
}

// ---------------------------------------------------------------------------
extern "C" void kernel_launch(void* const* d_in, const int* in_sizes, int n_in,
                              void* d_out, int out_size, void* d_ws, size_t ws_size,
                              hipStream_t stream) {
  const float* x = (const float*)d_in[0];
  const float* pos = (const float*)d_in[1];
  const int* ei = (const int*)d_in[2];
  const float* W1 = (const float*)d_in[3];
  const float* b1 = (const float*)d_in[4];
  const float* g1 = (const float*)d_in[5];
  const float* be1 = (const float*)d_in[6];
  const float* W2 = (const float*)d_in[7];
  const float* b2 = (const float*)d_in[8];
  const float* g2 = (const float*)d_in[9];
  const float* be2 = (const float*)d_in[10];
  const float* W3 = (const float*)d_in[11];
  const float* b3 = (const float*)d_in[12];
  const float* g3 = (const float*)d_in[13];
  const float* be3 = (const float*)d_in[14];

  int N = in_sizes[0] / 3;
  int E = in_sizes[2] / 2;
  int NB = (N + NPB - 1) / NPB;
  long n_out = (long)N * 64;

  char* wsb = (char*)d_ws;
  u16* h = (u16*)wsb;  // [E,64] bf16 activations, in sorted-slot order
  size_t off = (size_t)E * 64 * 2;
  float* stats = (float*)(wsb + off);
  off += 1024 * 4;
  u32* bucketTotal = (u32*)(wsb + off);
  off += (NBMAX + 1) * 4;
  u32* baseArr = (u32*)(wsb + off);
  off += (NBMAX + 1) * 4;
  u32* cursor = (u32*)(wsb + off);
  off += NBMAX * 4;
  off = (off + 7) & ~(size_t)7;  // 8-align for uint2
  uint2* sorted2 = (uint2*)(wsb + off);
  off += (size_t)E * 8;
  u8* ln8 = (u8*)(wsb + off);
  off += (size_t)E;
  size_t need = off;

  float* gsum1 = stats + 64, * gsq1 = stats + 128;
  float* gsum2 = stats + 192, * gsq2 = stats + 256;
  float* gsum3 = stats + 320, * gsq3 = stats + 384;

  float* outf = (float*)d_out;
  float invE = 1.0f / (float)E;
  bool binned = (ws_size >= need) && (NB <= NBMAX);

  if (binned) {
    k_init<<<1, 1024, 0, stream>>>(stats, bucketTotal);
    k_norm_hist<<<256, 256, 0, stream>>>(ei, pos, E, NB, stats, bucketTotal);
    k_scan<<<1, 64, 0, stream>>>(bucketTotal, baseArr, cursor, NB);
    k_place<<<256, 256, 0, stream>>>(ei, E, NB, cursor, sorted2, ln8);
    k_layer1<<<1024, 256, 0, stream>>>(ei, pos, x, W1, b1, h, stats, gsum1, gsq1, E, sorted2);
    k_layer_mfma<<<1536, 256, 0, stream>>>(h, W2, b2, gsum1, gsq1, g1, be1, invE, gsum2, gsq2, E);
    k_layer_mfma<<<1536, 256, 0, stream>>>(h, W3, b3, gsum2, gsq2, g2, be2, invE, gsum3, gsq3, E);
    k_bucket_max<<<NB, 256, 0, stream>>>(ln8, baseArr, h, gsum3, gsq3, g3, be3, invE, outf, N);
  } else {
    k_initout<<<4096, 256, 0, stream>>>(outf, n_out, stats, bucketTotal);
    k_norm_hist<<<256, 256, 0, stream>>>(ei, pos, E, NB <= NBMAX ? NB : 1, stats, bucketTotal);
    k_layer1<<<1024, 256, 0, stream>>>(ei, pos, x, W1, b1, h, stats, gsum1, gsq1, E, (const uint2*)nullptr);
    k_layer_mfma<<<1536, 256, 0, stream>>>(h, W2, b2, gsum1, gsq1, g1, be1, invE, gsum2, gsq2, E);
    k_layer_mfma<<<1536, 256, 0, stream>>>(h, W3, b3, gsum2, gsq2, g2, be2, invE, gsum3, gsq3, E);
    k_scatter<<<2048, 256, 0, stream>>>(ei, h, gsum3, gsq3, g3, be3, invE, outf, E);
    k_out<<<2048, 256, 0, stream>>>(outf, n_out);
  }
}